// Round 1
// baseline (311.947 us; speedup 1.0000x reference)
//
#include <hip/hip_runtime.h>

#define SGRID 28
#define NBATCH 1024
constexpr int CELLS = NBATCH * SGRID * SGRID;   // 802816
constexpr float L_COORD = 5.0f;
constexpr float L_NOOBJ = 0.5f;

__global__ __launch_bounds__(256) void yolo_main(
    const float* __restrict__ pred,      // CELLS*30  (x,y,w,h,conf)*2 + 20 cls
    const float* __restrict__ tboxes,    // CELLS*4
    const float* __restrict__ tcls,      // CELLS*20
    const int*   __restrict__ objmap,    // CELLS (bool as int32)
    float* __restrict__ acc)             // ws: [reg_raw, cobj_raw, nbj_raw, cls_raw]
{
    int idx = blockIdx.x * blockDim.x + threadIdx.x;
    float reg = 0.f, cobj = 0.f, nbj = 0.f, clsv = 0.f;

    if (idx < CELLS) {
        // ---- loads ----
        float p[30];
        const float2* p2 = reinterpret_cast<const float2*>(pred + (size_t)idx * 30);
        #pragma unroll
        for (int i = 0; i < 15; ++i) { float2 v = p2[i]; p[2*i] = v.x; p[2*i+1] = v.y; }

        float4 tbv = reinterpret_cast<const float4*>(tboxes)[idx];

        float tcl[20];
        const float4* tc4 = reinterpret_cast<const float4*>(tcls + (size_t)idx * 20);
        #pragma unroll
        for (int i = 0; i < 5; ++i) {
            float4 v = tc4[i];
            tcl[4*i] = v.x; tcl[4*i+1] = v.y; tcl[4*i+2] = v.z; tcl[4*i+3] = v.w;
        }

        bool obj = objmap[idx] != 0;

        // ---- classification loss (raw sum) ----
        float cs = 0.f;
        #pragma unroll
        for (int j = 0; j < 20; ++j) { float d = p[10 + j] - tcl[j]; cs += d * d; }
        clsv = obj ? cs : 0.f;

        // ---- no-object conf loss (raw sum) ----
        float c0 = p[4], c1 = p[9];
        nbj = obj ? 0.f : (c0 * c0 + c1 * c1);

        // ---- boxes: xywh -> xyxy, IoU ----
        const float invS = 1.0f / SGRID;
        float tx = tbv.x * invS, ty = tbv.y * invS;
        float thw = 0.5f * tbv.z, thh = 0.5f * tbv.w;
        float tx1 = tx - thw, ty1 = ty - thh, tx2 = tx + thw, ty2 = ty + thh;
        float ta = (tx2 - tx1) * (ty2 - ty1);

        float bx1[2], by1[2], bx2[2], by2[2], bcf[2], biou[2];
        #pragma unroll
        for (int b = 0; b < 2; ++b) {
            const float* q = p + b * 5;
            float cx = q[0] * invS, cy = q[1] * invS;
            float hw = 0.5f * q[2], hh = 0.5f * q[3];
            float x1 = cx - hw, y1 = cy - hh, x2 = cx + hw, y2 = cy + hh;
            bx1[b] = x1; by1[b] = y1; bx2[b] = x2; by2[b] = y2; bcf[b] = q[4];
            float ltx = fmaxf(x1, tx1), lty = fmaxf(y1, ty1);
            float rbx = fminf(x2, tx2), rby = fminf(y2, ty2);
            float wi = fmaxf(rbx - ltx, 0.f), hi = fmaxf(rby - lty, 0.f);
            float inter = wi * hi;
            float a1 = (x2 - x1) * (y2 - y1);
            biou[b] = inter / (a1 + ta - inter);
        }
        int sel = (biou[1] > biou[0]) ? 1 : 0;   // argmax, first-on-tie
        float best_iou = biou[sel];
        bool valid = best_iou > 0.f;
        float bbx1 = valid ? bx1[sel] : 0.f;
        float bby1 = valid ? by1[sel] : 0.f;
        float bbx2 = valid ? bx2[sel] : 0.f;
        float bby2 = valid ? by2[sel] : 0.f;
        float bcfs = valid ? bcf[sel] : 0.f;
        best_iou   = valid ? best_iou : 0.f;

        // ---- regression (raw: loss_xy + loss_wh) ----
        float dx = bbx1 - tx1, dy = bby1 - ty1;
        float lxy = dx * dx + dy * dy;
        auto ssqrt = [](float x) { return x > 0.f ? sqrtf(x) : 0.f; };
        float dwx = ssqrt(bbx2) - ssqrt(tx2);
        float dwy = ssqrt(bby2) - ssqrt(ty2);
        float lwh = dwx * dwx + dwy * dwy;
        reg = obj ? (lxy + lwh) : 0.f;

        // ---- contains-object conf loss (raw) ----
        float dc = bcfs - best_iou;
        cobj = obj ? dc * dc : 0.f;
    }

    // ---- reduction: wave64 shuffle, then cross-wave via LDS ----
    #pragma unroll
    for (int off = 32; off > 0; off >>= 1) {
        reg  += __shfl_down(reg,  off);
        cobj += __shfl_down(cobj, off);
        nbj  += __shfl_down(nbj,  off);
        clsv += __shfl_down(clsv, off);
    }
    __shared__ float sred[4][4];
    int wave = threadIdx.x >> 6;
    int lane = threadIdx.x & 63;
    if (lane == 0) {
        sred[wave][0] = reg; sred[wave][1] = cobj;
        sred[wave][2] = nbj; sred[wave][3] = clsv;
    }
    __syncthreads();
    if (threadIdx.x == 0) {
        float r = 0, c = 0, n = 0, cl = 0;
        #pragma unroll
        for (int w = 0; w < 4; ++w) {
            r += sred[w][0]; c += sred[w][1]; n += sred[w][2]; cl += sred[w][3];
        }
        atomicAdd(&acc[0], r);
        atomicAdd(&acc[1], c);
        atomicAdd(&acc[2], n);
        atomicAdd(&acc[3], cl);
    }
}

__global__ void yolo_finalize(const float* __restrict__ acc, float* __restrict__ out) {
    if (threadIdx.x == 0) {
        float invN = 1.0f / NBATCH;
        float reg_l  = L_COORD * acc[0] * invN;
        float cobj_l = acc[1] * invN;
        float nbj_l  = L_NOOBJ * acc[2] * invN;
        float cls_l  = 2.0f * acc[3] * invN;
        out[0] = cls_l + nbj_l + reg_l + cobj_l;  // total
        out[1] = reg_l;
        out[2] = cobj_l;
        out[3] = nbj_l;
        out[4] = cls_l;
    }
}

extern "C" void kernel_launch(void* const* d_in, const int* in_sizes, int n_in,
                              void* d_out, int out_size, void* d_ws, size_t ws_size,
                              hipStream_t stream) {
    const float* pred   = (const float*)d_in[0];
    const float* tboxes = (const float*)d_in[1];
    const float* tcls   = (const float*)d_in[2];
    const int*   objmap = (const int*)d_in[3];
    float* acc = (float*)d_ws;
    float* out = (float*)d_out;

    hipMemsetAsync(acc, 0, 4 * sizeof(float), stream);
    int grid = (CELLS + 255) / 256;   // 3136 exactly
    yolo_main<<<grid, 256, 0, stream>>>(pred, tboxes, tcls, objmap, acc);
    yolo_finalize<<<1, 64, 0, stream>>>(acc, out);
}

// Round 2
// 202.444 us; speedup vs baseline: 1.5409x; 1.5409x over previous
//
#include <hip/hip_runtime.h>

#define SGRID 28
#define NBATCH 1024
constexpr int CELLS = NBATCH * SGRID * SGRID;   // 802816
constexpr int CPB   = 256;                      // cells per block
constexpr int NBLK  = CELLS / CPB;              // 3136
constexpr float L_COORD = 5.0f;
constexpr float L_NOOBJ = 0.5f;

__global__ __launch_bounds__(256) void yolo_main(
    const float* __restrict__ pred,      // CELLS*30
    const float* __restrict__ tboxes,    // CELLS*4
    const float* __restrict__ tcls,      // CELLS*20
    const int*   __restrict__ objmap,    // CELLS
    float4* __restrict__ partials)       // NBLK partial sums: {reg, cobj, nbj, cls}
{
    __shared__ float sp[CPB * 30];       // 30720 B pred slab
    __shared__ float smask[CPB];         // 1024 B
    __shared__ float sred[4][4];

    const int tid  = threadIdx.x;
    const int base = blockIdx.x * CPB;

    // ---- coalesced own-cell loads (unit stride across lanes) ----
    float fm = (objmap[base + tid] != 0) ? 1.f : 0.f;
    smask[tid] = fm;
    float4 tbv = reinterpret_cast<const float4*>(tboxes)[base + tid];

    // ---- stage pred slab into LDS, fully coalesced float4 ----
    const float4* p4 = reinterpret_cast<const float4*>(pred) + (size_t)base * 30 / 4;
    float4* sp4 = reinterpret_cast<float4*>(sp);
    #pragma unroll
    for (int i = 0; i < 7; ++i) sp4[tid + i * 256] = p4[tid + i * 256];
    if (tid < 128) sp4[tid + 1792] = p4[tid + 1792];   // 1920 total
    __syncthreads();

    // ---- box math: thread t = cell t (LDS stride 30 floats -> 2-way, free) ----
    const float* q = sp + tid * 30;
    float reg, cobj, nbj;
    {
        const float invS = 1.0f / SGRID;
        float tx = tbv.x * invS, ty = tbv.y * invS;
        float thw = 0.5f * tbv.z, thh = 0.5f * tbv.w;
        float tx1 = tx - thw, ty1 = ty - thh, tx2 = tx + thw, ty2 = ty + thh;
        float ta = (tx2 - tx1) * (ty2 - ty1);

        float bx1[2], by1[2], bx2[2], by2[2], bcf[2], biou[2];
        #pragma unroll
        for (int b = 0; b < 2; ++b) {
            float cx = q[b*5+0] * invS, cy = q[b*5+1] * invS;
            float hw = 0.5f * q[b*5+2], hh = 0.5f * q[b*5+3];
            float x1 = cx - hw, y1 = cy - hh, x2 = cx + hw, y2 = cy + hh;
            bx1[b] = x1; by1[b] = y1; bx2[b] = x2; by2[b] = y2; bcf[b] = q[b*5+4];
            float ltx = fmaxf(x1, tx1), lty = fmaxf(y1, ty1);
            float rbx = fminf(x2, tx2), rby = fminf(y2, ty2);
            float wi = fmaxf(rbx - ltx, 0.f), hi = fmaxf(rby - lty, 0.f);
            float inter = wi * hi;
            float a1 = (x2 - x1) * (y2 - y1);
            biou[b] = inter / (a1 + ta - inter);
        }
        int sel = (biou[1] > biou[0]) ? 1 : 0;
        float best_iou = biou[sel];
        bool valid = best_iou > 0.f;
        float bbx1 = valid ? bx1[sel] : 0.f;
        float bby1 = valid ? by1[sel] : 0.f;
        float bbx2 = valid ? bx2[sel] : 0.f;
        float bby2 = valid ? by2[sel] : 0.f;
        float bcfs = valid ? bcf[sel] : 0.f;
        best_iou   = valid ? best_iou : 0.f;

        float dx = bbx1 - tx1, dy = bby1 - ty1;
        float lxy = dx * dx + dy * dy;
        auto ssqrt = [](float x) { return x > 0.f ? sqrtf(x) : 0.f; };
        float dwx = ssqrt(bbx2) - ssqrt(tx2);
        float dwy = ssqrt(bby2) - ssqrt(ty2);
        float lwh = dwx * dwx + dwy * dwy;
        reg = fm * (lxy + lwh);

        float c0 = q[4], c1 = q[9];
        nbj = (1.f - fm) * (c0 * c0 + c1 * c1);

        float dc = bcfs - best_iou;
        cobj = fm * dc * dc;
    }

    // ---- cls loss: flat coalesced float4 over tcls, pred from LDS ----
    float clsv = 0.f;
    const float4* tc4 = reinterpret_cast<const float4*>(tcls) + (size_t)base * 5;
    #pragma unroll
    for (int i = 0; i < 5; ++i) {
        int e = tid + i * 256;           // [0, 1280)
        float4 tv = tc4[e];
        int cell = e / 5;
        int c0   = (e - cell * 5) * 4;
        const float* pc = sp + cell * 30 + 10 + c0;
        float mk = smask[cell];
        float d0 = pc[0] - tv.x, d1 = pc[1] - tv.y;
        float d2 = pc[2] - tv.z, d3 = pc[3] - tv.w;
        clsv += mk * (d0 * d0 + d1 * d1 + d2 * d2 + d3 * d3);
    }

    // ---- reduction: wave64 shuffle, then cross-wave via LDS ----
    #pragma unroll
    for (int off = 32; off > 0; off >>= 1) {
        reg  += __shfl_down(reg,  off);
        cobj += __shfl_down(cobj, off);
        nbj  += __shfl_down(nbj,  off);
        clsv += __shfl_down(clsv, off);
    }
    int wave = tid >> 6, lane = tid & 63;
    if (lane == 0) {
        sred[wave][0] = reg; sred[wave][1] = cobj;
        sred[wave][2] = nbj; sred[wave][3] = clsv;
    }
    __syncthreads();
    if (tid == 0) {
        float4 s;
        s.x = sred[0][0] + sred[1][0] + sred[2][0] + sred[3][0];
        s.y = sred[0][1] + sred[1][1] + sred[2][1] + sred[3][1];
        s.z = sred[0][2] + sred[1][2] + sred[2][2] + sred[3][2];
        s.w = sred[0][3] + sred[1][3] + sred[2][3] + sred[3][3];
        partials[blockIdx.x] = s;
    }
}

__global__ __launch_bounds__(256) void yolo_finalize(
    const float4* __restrict__ partials, float* __restrict__ out)
{
    float4 s = {0.f, 0.f, 0.f, 0.f};
    for (int b = threadIdx.x; b < NBLK; b += 256) {
        float4 v = partials[b];
        s.x += v.x; s.y += v.y; s.z += v.z; s.w += v.w;
    }
    #pragma unroll
    for (int off = 32; off > 0; off >>= 1) {
        s.x += __shfl_down(s.x, off);
        s.y += __shfl_down(s.y, off);
        s.z += __shfl_down(s.z, off);
        s.w += __shfl_down(s.w, off);
    }
    __shared__ float4 sw[4];
    int wave = threadIdx.x >> 6, lane = threadIdx.x & 63;
    if (lane == 0) sw[wave] = s;
    __syncthreads();
    if (threadIdx.x == 0) {
        float r = 0.f, c = 0.f, n = 0.f, cl = 0.f;
        #pragma unroll
        for (int w = 0; w < 4; ++w) {
            r += sw[w].x; c += sw[w].y; n += sw[w].z; cl += sw[w].w;
        }
        const float invN = 1.0f / NBATCH;
        float reg_l  = L_COORD * r * invN;
        float cobj_l = c * invN;
        float nbj_l  = L_NOOBJ * n * invN;
        float cls_l  = 2.0f * cl * invN;
        out[0] = cls_l + nbj_l + reg_l + cobj_l;
        out[1] = reg_l;
        out[2] = cobj_l;
        out[3] = nbj_l;
        out[4] = cls_l;
    }
}

extern "C" void kernel_launch(void* const* d_in, const int* in_sizes, int n_in,
                              void* d_out, int out_size, void* d_ws, size_t ws_size,
                              hipStream_t stream) {
    const float* pred   = (const float*)d_in[0];
    const float* tboxes = (const float*)d_in[1];
    const float* tcls   = (const float*)d_in[2];
    const int*   objmap = (const int*)d_in[3];
    float4* partials = (float4*)d_ws;
    float*  out      = (float*)d_out;

    yolo_main<<<NBLK, 256, 0, stream>>>(pred, tboxes, tcls, objmap, partials);
    yolo_finalize<<<1, 256, 0, stream>>>(partials, out);
}